// Round 15
// baseline (76.063 us; speedup 1.0000x reference)
//
#include <hip/hip_runtime.h>

#define H 65536
#define CIN 64
#define COUT 128
#define NK 27
#define KTOT (NK*CIN)   // 1728
#define NBLK 256        // points per block; 16 waves = 8 wo x 2 wn (16o x 128n)
#define NTHR 1024
#define NBLOCKS (H/NBLK) // 256

typedef unsigned short u16;
typedef unsigned int   u32;
typedef __attribute__((ext_vector_type(8))) short short8;   // 8 bf16 (MFMA frag)
typedef __attribute__((ext_vector_type(8))) unsigned short ushort8;
typedef __attribute__((ext_vector_type(4))) float f32x4;    // MFMA acc
typedef __attribute__((ext_vector_type(4))) unsigned int u32x4;

__device__ __forceinline__ u16 f2bf(float f) {
    u32 u = __float_as_uint(f);
    u = (u + 0x7FFFu + ((u >> 16) & 1u)) >> 16;   // RNE
    return (u16)u;
}
__device__ __forceinline__ float bf2f(u16 v) {
    u32 u = (u32)v << 16;
    return __uint_as_float(u);
}

// ---------------------------------------------------------------------------
// Kernel 1 (fused prep): blocks 0..255 transpose x -> xt (point-major bf16);
// blocks 256..1119 repack w -> wb[o][k*64+c] bf16; block 256 zeroes sums.
__global__ __launch_bounds__(256) void prep(const float* __restrict__ x,
                                            const float* __restrict__ w,
                                            u16* __restrict__ xt,
                                            u16* __restrict__ wb,
                                            float* __restrict__ sums) {
    const int b = blockIdx.x;
    if (b < 256) {
        const int h = b * 256 + threadIdx.x;
        u32 pk[32];
#pragma unroll
        for (int cp = 0; cp < 32; ++cp) {
            float f0 = x[(2 * cp)     * H + h];
            float f1 = x[(2 * cp + 1) * H + h];
            pk[cp] = (u32)f2bf(f0) | ((u32)f2bf(f1) << 16);
        }
        u32x4* dst = (u32x4*)(xt + (size_t)h * CIN);
#pragma unroll
        for (int i = 0; i < 8; ++i)
            dst[i] = *(u32x4*)&pk[i * 4];
    } else {
        if (b == 256) sums[threadIdx.x] = 0.f;   // sum[128], sumsq[128]
        const int tid = (b - 256) * 256 + threadIdx.x;
        if (tid < COUT * KTOT) {
            const int o = tid / KTOT;
            const int rem = tid - o * KTOT;
            const int k = rem >> 6;
            const int c = rem & 63;
            wb[tid] = f2bf(w[o * KTOT + c * NK + k]);
        }
    }
}

// ---------------------------------------------------------------------------
// Kernel 2: R14 conv (3-buffer ring, 1 barrier/k, 54.8us) with ONE change:
// output stored as bf16 to scratch (halves conv WRITE + bn_relu READ).
__global__ __launch_bounds__(NTHR, 4) void conv_mfma(const u16* __restrict__ xt,
                                                     const u16* __restrict__ wb,
                                                     const int* __restrict__ neigh,
                                                     u16* __restrict__ obuf,
                                                     float* __restrict__ part) {
    __shared__ __align__(16) u16 sB[3][NBLK * CIN];  // 3 x 32 KB ring
    __shared__ u16 sIdx[NBLK * NK];                  // 13824 B (reused as f32 red)

    const int tid  = threadIdx.x;
    const int lane = tid & 63;
    const int w    = tid >> 6;        // wave 0..15
    const int wo   = w >> 1;          // o-block 0..7  (16 o each)
    const int wn   = w & 1;           // n-half 0..1   (128 n each)
    const int n0   = blockIdx.x * NBLK;

    for (int i = tid; i < NBLK * NK; i += NTHR)
        sIdx[i] = (u16)neigh[n0 * NK + i];
    __syncthreads();                   // once, before the pipeline

    const int r16 = lane & 15;
    const int q   = lane >> 4;        // 0..3
    const int kc  = q * 8;
    const int pl  = lane >> 3;        // 0..7 row-within-8
    const int cl  = lane & 7;         // 16B chunk within 128B row

    f32x4 acc[8] = {};                // [n-frag]

    u32x4  rg[2][2];                  // gather regs: g(k) in rg[k&1][it]
    short8 af[2][2];                  // A regs: A(k) in af[k&1][hh]

#define GATHER(K)                                                            \
    { _Pragma("unroll") for (int it = 0; it < 2; ++it) {                     \
        const int p_ = w * 16 + it * 8 + pl;                                 \
        const int row_ = sIdx[p_ * NK + (K)];                                \
        rg[(K) & 1][it] =                                                    \
            *(const u32x4*)(xt + (size_t)(u32)row_ * 64 + cl * 8); } }
#define WRITEB(K)                                                            \
    { _Pragma("unroll") for (int it = 0; it < 2; ++it) {                     \
        const int p_ = w * 16 + it * 8 + pl;                                 \
        *(u32x4*)(&sB[(K) % 3][p_ * 64 + ((cl ^ pl) * 8)]) = rg[(K) & 1][it]; } }
#define A_LOAD(K)                                                            \
    { _Pragma("unroll") for (int hh = 0; hh < 2; ++hh) {                     \
        const int o_ = wo * 16 + r16;                                        \
        af[(K) & 1][hh] = *(const short8*)(wb + (size_t)o_ * KTOT +          \
                                           (K) * CIN + hh * 32 + kc); } }
#define MFMA_STEP(K)                                                         \
    { _Pragma("unroll") for (int hh = 0; hh < 2; ++hh)                       \
      _Pragma("unroll") for (int g2 = 0; g2 < 2; ++g2) {                     \
        short8 bfr[4];                                                       \
        _Pragma("unroll") for (int j = 0; j < 4; ++j) {                      \
            const int nf = g2 * 4 + j;                                       \
            const int p_ = wn * 128 + nf * 16 + r16;                         \
            const int sl_ = (hh * 4 + q) ^ (p_ & 7);                         \
            bfr[j] = *(const short8*)(&sB[(K) % 3][p_ * 64 + sl_ * 8]);      \
        }                                                                    \
        _Pragma("unroll") for (int j = 0; j < 4; ++j)                        \
            acc[g2 * 4 + j] = __builtin_amdgcn_mfma_f32_16x16x32_bf16(       \
                af[(K) & 1][hh], bfr[j], acc[g2 * 4 + j], 0, 0, 0);          \
    } }

    // prologue: buf0,buf1 staged; g(2),g(3) in flight; A(0) loaded
    GATHER(0)
    GATHER(1)
    WRITEB(0)
    WRITEB(1)
    A_LOAD(0)
    GATHER(2)
    GATHER(3)
    asm volatile("s_waitcnt lgkmcnt(0)" ::: "memory");   // buf0/1 writes done

#pragma unroll
    for (int k = 0; k < NK; ++k) {
        __builtin_amdgcn_s_barrier();     // fences readers of buf[(k+2)%3]
        if (k + 2 < NK) WRITEB(k + 2)     // waits g(k+2) via counted vmcnt
        if (k + 1 < NK) A_LOAD(k + 1)
        if (k + 4 < NK) GATHER(k + 4)
        MFMA_STEP(k)                       // reads buf[k%3], written 2 bars ago
        asm volatile("s_waitcnt lgkmcnt(0)" ::: "memory"); // my WR visible pre-next-bar
    }

#undef GATHER
#undef WRITEB
#undef A_LOAD
#undef MFMA_STEP

    // epilogue: C/D layout: col(n) = lane&15, row(o) = q*4 + r. bf16 store.
#pragma unroll
    for (int nf = 0; nf < 8; ++nf)
#pragma unroll
        for (int r = 0; r < 4; ++r) {
            const int o = wo * 16 + q * 4 + r;
            const int n = n0 + wn * 128 + nf * 16 + r16;
            obuf[(size_t)o * H + n] = f2bf(acc[nf][r]);
        }

    // BN partials: reduce this wave's 128 n per o (f32 acc, exact path);
    // two wn-halves write disjoint LDS slots; fold + coalesced store.
    float* red = (float*)sIdx;        // reuse; all gathers done
    __syncthreads();
#pragma unroll
    for (int r = 0; r < 4; ++r) {
        float sv = 0.f, sq = 0.f;
#pragma unroll
        for (int nf = 0; nf < 8; ++nf) {
            sv += acc[nf][r];
            sq += acc[nf][r] * acc[nf][r];
        }
#pragma unroll
        for (int m = 1; m < 16; m <<= 1) {
            sv += __shfl_xor(sv, m, 64);
            sq += __shfl_xor(sq, m, 64);
        }
        if (r16 == 0) {
            const int o = wo * 16 + q * 4 + r;
            red[wn * 256 + o]       = sv;   // sums: slots 0..127 per half
            red[wn * 256 + 128 + o] = sq;   // sumsq
        }
    }
    __syncthreads();
    if (tid < 128) {
        part[(size_t)blockIdx.x * 256 + tid]       = red[tid] + red[256 + tid];
        part[(size_t)blockIdx.x * 256 + 128 + tid] = red[128 + tid] + red[384 + tid];
    }
}

// ---------------------------------------------------------------------------
// Kernel 2b: fold 256 per-block partials into sums[256]. 16 atomics/address.
__global__ __launch_bounds__(256) void bn_reduce(const float* __restrict__ part,
                                                 float* __restrict__ sums) {
    const int tid = threadIdx.x;
    float s = 0.f;
    const int b0 = blockIdx.x * (NBLOCKS / 16);
    for (int b = b0; b < b0 + NBLOCKS / 16; ++b)
        s += part[(size_t)b * 256 + tid];
    atomicAdd(&sums[tid], s);
}

// ---------------------------------------------------------------------------
// Kernel 3: BN + ReLU. Reads bf16 obuf (16MB), writes f32 out (32MB).
// Block = (o, 1/16 of the row): 256 thr x 16 values.
__global__ __launch_bounds__(256) void bn_relu(const u16* __restrict__ obuf,
                                               const float* __restrict__ sums,
                                               const float* __restrict__ gamma,
                                               const float* __restrict__ beta,
                                               float* __restrict__ out) {
    const int o     = blockIdx.x >> 4;
    const int chunk = blockIdx.x & 15;
    const float mean = sums[o] * (1.f / (float)H);
    const float var  = sums[COUT + o] * (1.f / (float)H) - mean * mean;
    const float a = gamma[o] * rsqrtf(var + 1e-5f);
    const float b = beta[o] - mean * a;
    const size_t base = (size_t)o * H + chunk * 4096 + threadIdx.x * 16;
    const ushort8* src = (const ushort8*)(obuf + base);
    float4* dst = (float4*)(out + base);
#pragma unroll
    for (int v = 0; v < 2; ++v) {
        ushort8 u = src[v];
        float4 f0, f1;
        f0.x = fmaxf(fmaf(bf2f(u[0]), a, b), 0.f);
        f0.y = fmaxf(fmaf(bf2f(u[1]), a, b), 0.f);
        f0.z = fmaxf(fmaf(bf2f(u[2]), a, b), 0.f);
        f0.w = fmaxf(fmaf(bf2f(u[3]), a, b), 0.f);
        f1.x = fmaxf(fmaf(bf2f(u[4]), a, b), 0.f);
        f1.y = fmaxf(fmaf(bf2f(u[5]), a, b), 0.f);
        f1.z = fmaxf(fmaf(bf2f(u[6]), a, b), 0.f);
        f1.w = fmaxf(fmaf(bf2f(u[7]), a, b), 0.f);
        dst[v * 2]     = f0;
        dst[v * 2 + 1] = f1;
    }
}

// ---------------------------------------------------------------------------
extern "C" void kernel_launch(void* const* d_in, const int* in_sizes, int n_in,
                              void* d_out, int out_size, void* d_ws, size_t ws_size,
                              hipStream_t stream) {
    const float* x     = (const float*)d_in[0];  // (1,64,65536,1)
    const int*   neigh = (const int*)d_in[1];    // (65536,27)
    const float* w     = (const float*)d_in[2];  // (128,64,27)
    const float* gamma = (const float*)d_in[3];
    const float* beta  = (const float*)d_in[4];
    float* out = (float*)d_out;                  // (1,128,65536,1)

    char* ws = (char*)d_ws;
    u16* xt  = (u16*)ws;                              // 8388608 B
    u16* wb  = (u16*)(ws + 8388608);                  // 442368 B
    float* sums = (float*)(ws + 8830976);             // 1024 B
    float* part = (float*)(ws + 8832000);             // 256 KB
    u16* obuf = (u16*)(ws + 9094144);                 // 16 MB bf16 intermediate

    prep<<<1120, 256, 0, stream>>>(x, w, xt, wb, sums);
    conv_mfma<<<NBLOCKS, NTHR, 0, stream>>>(xt, wb, neigh, obuf, part);
    bn_reduce<<<16, 256, 0, stream>>>(part, sums);
    bn_relu<<<COUT * 16, 256, 0, stream>>>(obuf, sums, gamma, beta, out);
}

// Round 17
// 66.460 us; speedup vs baseline: 1.1445x; 1.1445x over previous
//
#include <hip/hip_runtime.h>

#define H 65536
#define CIN 64
#define COUT 128
#define NK 27
#define KTOT (NK*CIN)   // 1728
#define NBLK 256        // points per block; 16 waves = 8 wo x 2 wn (16o x 128n)
#define NTHR 1024
#define NBLOCKS (H/NBLK) // 256

typedef unsigned short u16;
typedef unsigned int   u32;
typedef __attribute__((ext_vector_type(8))) short short8;   // 8 bf16 (MFMA frag)
typedef __attribute__((ext_vector_type(4))) unsigned short bf16x4;
typedef __attribute__((ext_vector_type(4))) float f32x4;    // MFMA acc
typedef __attribute__((ext_vector_type(4))) unsigned int u32x4;

__device__ __forceinline__ u16 f2bf(float f) {
    u32 u = __float_as_uint(f);
    u = (u + 0x7FFFu + ((u >> 16) & 1u)) >> 16;   // RNE
    return (u16)u;
}
__device__ __forceinline__ float bf2f(u16 v) {
    u32 u = (u32)v << 16;
    return __uint_as_float(u);
}

// ---------------------------------------------------------------------------
// Kernel 1 (fused prep): blocks 0..255 transpose x -> xt (point-major bf16);
// blocks 256..1119 repack w -> wb[o][k*64+c] bf16; block 256 zeroes sums.
__global__ __launch_bounds__(256) void prep(const float* __restrict__ x,
                                            const float* __restrict__ w,
                                            u16* __restrict__ xt,
                                            u16* __restrict__ wb,
                                            float* __restrict__ sums) {
    const int b = blockIdx.x;
    if (b < 256) {
        const int h = b * 256 + threadIdx.x;
        u32 pk[32];
#pragma unroll
        for (int cp = 0; cp < 32; ++cp) {
            float f0 = x[(2 * cp)     * H + h];
            float f1 = x[(2 * cp + 1) * H + h];
            pk[cp] = (u32)f2bf(f0) | ((u32)f2bf(f1) << 16);
        }
        u32x4* dst = (u32x4*)(xt + (size_t)h * CIN);
#pragma unroll
        for (int i = 0; i < 8; ++i)
            dst[i] = *(u32x4*)&pk[i * 4];
    } else {
        if (b == 256) sums[threadIdx.x] = 0.f;   // sum[128], sumsq[128]
        const int tid = (b - 256) * 256 + threadIdx.x;
        if (tid < COUT * KTOT) {
            const int o = tid / KTOT;
            const int rem = tid - o * KTOT;
            const int k = rem >> 6;
            const int c = rem & 63;
            wb[tid] = f2bf(w[o * KTOT + c * NK + k]);
        }
    }
}

// ---------------------------------------------------------------------------
// Kernel 2: R14/R15 conv (3-buffer ring, 1 barrier/k, bf16 output, 51.9us).
__global__ __launch_bounds__(NTHR, 4) void conv_mfma(const u16* __restrict__ xt,
                                                     const u16* __restrict__ wb,
                                                     const int* __restrict__ neigh,
                                                     u16* __restrict__ obuf,
                                                     float* __restrict__ part) {
    __shared__ __align__(16) u16 sB[3][NBLK * CIN];  // 3 x 32 KB ring
    __shared__ u16 sIdx[NBLK * NK];                  // 13824 B (reused as f32 red)

    const int tid  = threadIdx.x;
    const int lane = tid & 63;
    const int w    = tid >> 6;        // wave 0..15
    const int wo   = w >> 1;          // o-block 0..7  (16 o each)
    const int wn   = w & 1;           // n-half 0..1   (128 n each)
    const int n0   = blockIdx.x * NBLK;

    for (int i = tid; i < NBLK * NK; i += NTHR)
        sIdx[i] = (u16)neigh[n0 * NK + i];
    __syncthreads();                   // once, before the pipeline

    const int r16 = lane & 15;
    const int q   = lane >> 4;        // 0..3
    const int kc  = q * 8;
    const int pl  = lane >> 3;        // 0..7 row-within-8
    const int cl  = lane & 7;         // 16B chunk within 128B row

    f32x4 acc[8] = {};                // [n-frag]

    u32x4  rg[2][2];                  // gather regs: g(k) in rg[k&1][it]
    short8 af[2][2];                  // A regs: A(k) in af[k&1][hh]

#define GATHER(K)                                                            \
    { _Pragma("unroll") for (int it = 0; it < 2; ++it) {                     \
        const int p_ = w * 16 + it * 8 + pl;                                 \
        const int row_ = sIdx[p_ * NK + (K)];                                \
        rg[(K) & 1][it] =                                                    \
            *(const u32x4*)(xt + (size_t)(u32)row_ * 64 + cl * 8); } }
#define WRITEB(K)                                                            \
    { _Pragma("unroll") for (int it = 0; it < 2; ++it) {                     \
        const int p_ = w * 16 + it * 8 + pl;                                 \
        *(u32x4*)(&sB[(K) % 3][p_ * 64 + ((cl ^ pl) * 8)]) = rg[(K) & 1][it]; } }
#define A_LOAD(K)                                                            \
    { _Pragma("unroll") for (int hh = 0; hh < 2; ++hh) {                     \
        const int o_ = wo * 16 + r16;                                        \
        af[(K) & 1][hh] = *(const short8*)(wb + (size_t)o_ * KTOT +          \
                                           (K) * CIN + hh * 32 + kc); } }
#define MFMA_STEP(K)                                                         \
    { _Pragma("unroll") for (int hh = 0; hh < 2; ++hh)                       \
      _Pragma("unroll") for (int g2 = 0; g2 < 2; ++g2) {                     \
        short8 bfr[4];                                                       \
        _Pragma("unroll") for (int j = 0; j < 4; ++j) {                      \
            const int nf = g2 * 4 + j;                                       \
            const int p_ = wn * 128 + nf * 16 + r16;                         \
            const int sl_ = (hh * 4 + q) ^ (p_ & 7);                         \
            bfr[j] = *(const short8*)(&sB[(K) % 3][p_ * 64 + sl_ * 8]);      \
        }                                                                    \
        _Pragma("unroll") for (int j = 0; j < 4; ++j)                        \
            acc[g2 * 4 + j] = __builtin_amdgcn_mfma_f32_16x16x32_bf16(       \
                af[(K) & 1][hh], bfr[j], acc[g2 * 4 + j], 0, 0, 0);          \
    } }

    // prologue: buf0,buf1 staged; g(2),g(3) in flight; A(0) loaded
    GATHER(0)
    GATHER(1)
    WRITEB(0)
    WRITEB(1)
    A_LOAD(0)
    GATHER(2)
    GATHER(3)
    asm volatile("s_waitcnt lgkmcnt(0)" ::: "memory");   // buf0/1 writes done

#pragma unroll
    for (int k = 0; k < NK; ++k) {
        __builtin_amdgcn_s_barrier();     // fences readers of buf[(k+2)%3]
        if (k + 2 < NK) WRITEB(k + 2)     // waits g(k+2) via counted vmcnt
        if (k + 1 < NK) A_LOAD(k + 1)
        if (k + 4 < NK) GATHER(k + 4)
        MFMA_STEP(k)                       // reads buf[k%3], written 2 bars ago
        asm volatile("s_waitcnt lgkmcnt(0)" ::: "memory"); // my WR visible pre-next-bar
    }

#undef GATHER
#undef WRITEB
#undef A_LOAD
#undef MFMA_STEP

    // epilogue: C/D layout: col(n) = lane&15, row(o) = q*4 + r. bf16 store.
#pragma unroll
    for (int nf = 0; nf < 8; ++nf)
#pragma unroll
        for (int r = 0; r < 4; ++r) {
            const int o = wo * 16 + q * 4 + r;
            const int n = n0 + wn * 128 + nf * 16 + r16;
            obuf[(size_t)o * H + n] = f2bf(acc[nf][r]);
        }

    // BN partials: reduce this wave's 128 n per o (f32 acc, exact path);
    // two wn-halves write disjoint LDS slots; fold + coalesced store.
    float* red = (float*)sIdx;        // reuse; all gathers done
    __syncthreads();
#pragma unroll
    for (int r = 0; r < 4; ++r) {
        float sv = 0.f, sq = 0.f;
#pragma unroll
        for (int nf = 0; nf < 8; ++nf) {
            sv += acc[nf][r];
            sq += acc[nf][r] * acc[nf][r];
        }
#pragma unroll
        for (int m = 1; m < 16; m <<= 1) {
            sv += __shfl_xor(sv, m, 64);
            sq += __shfl_xor(sq, m, 64);
        }
        if (r16 == 0) {
            const int o = wo * 16 + q * 4 + r;
            red[wn * 256 + o]       = sv;   // sums: slots 0..127 per half
            red[wn * 256 + 128 + o] = sq;   // sumsq
        }
    }
    __syncthreads();
    if (tid < 128) {
        part[(size_t)blockIdx.x * 256 + tid]       = red[tid] + red[256 + tid];
        part[(size_t)blockIdx.x * 256 + 128 + tid] = red[128 + tid] + red[384 + tid];
    }
}

// ---------------------------------------------------------------------------
// Kernel 2b: fold 256 per-block partials into sums[256]. 16 atomics/address.
__global__ __launch_bounds__(256) void bn_reduce(const float* __restrict__ part,
                                                 float* __restrict__ sums) {
    const int tid = threadIdx.x;
    float s = 0.f;
    const int b0 = blockIdx.x * (NBLOCKS / 16);
    for (int b = b0; b < b0 + NBLOCKS / 16; ++b)
        s += part[(size_t)b * 256 + tid];
    atomicAdd(&sums[tid], s);
}

// ---------------------------------------------------------------------------
// Kernel 3: BN + ReLU, FULLY COALESCED: one 8B bf16x4 read + one 16B float4
// write per thread, lane-contiguous (R15's 16-val/thread chunking made
// partial-line strided stores -> RMW amplification; this is R14's access
// shape with bf16 input).
__global__ __launch_bounds__(256) void bn_relu(const u16* __restrict__ obuf,
                                               const float* __restrict__ sums,
                                               const float* __restrict__ gamma,
                                               const float* __restrict__ beta,
                                               float* __restrict__ out) {
    const int idx = blockIdx.x * 256 + threadIdx.x;  // 4-value chunk index
    const int o = idx >> 14;                          // 16384 chunks per channel
    const float mean = sums[o] * (1.f / (float)H);
    const float var  = sums[COUT + o] * (1.f / (float)H) - mean * mean;
    const float a = gamma[o] * rsqrtf(var + 1e-5f);
    const float b = beta[o] - mean * a;
    bf16x4 u = ((const bf16x4*)obuf)[idx];
    float4 f;
    f.x = fmaxf(fmaf(bf2f(u[0]), a, b), 0.f);
    f.y = fmaxf(fmaf(bf2f(u[1]), a, b), 0.f);
    f.z = fmaxf(fmaf(bf2f(u[2]), a, b), 0.f);
    f.w = fmaxf(fmaf(bf2f(u[3]), a, b), 0.f);
    ((float4*)out)[idx] = f;
}

// ---------------------------------------------------------------------------
extern "C" void kernel_launch(void* const* d_in, const int* in_sizes, int n_in,
                              void* d_out, int out_size, void* d_ws, size_t ws_size,
                              hipStream_t stream) {
    const float* x     = (const float*)d_in[0];  // (1,64,65536,1)
    const int*   neigh = (const int*)d_in[1];    // (65536,27)
    const float* w     = (const float*)d_in[2];  // (128,64,27)
    const float* gamma = (const float*)d_in[3];
    const float* beta  = (const float*)d_in[4];
    float* out = (float*)d_out;                  // (1,128,65536,1)

    char* ws = (char*)d_ws;
    u16* xt  = (u16*)ws;                              // 8388608 B
    u16* wb  = (u16*)(ws + 8388608);                  // 442368 B
    float* sums = (float*)(ws + 8830976);             // 1024 B
    float* part = (float*)(ws + 8832000);             // 256 KB
    u16* obuf = (u16*)(ws + 9094144);                 // 16 MB bf16 intermediate

    prep<<<1120, 256, 0, stream>>>(x, w, xt, wb, sums);
    conv_mfma<<<NBLOCKS, NTHR, 0, stream>>>(xt, wb, neigh, obuf, part);
    bn_reduce<<<16, 256, 0, stream>>>(part, sums);
    bn_relu<<<(COUT * H / 4) / 256, 256, 0, stream>>>(obuf, sums, gamma, beta, out);
}